// Round 12
// baseline (576.180 us; speedup 1.0000x reference)
//
#include <hip/hip_runtime.h>
#include <hip/hip_bf16.h>

#define B 4
#define S 1024
#define D 768
#define H 12
#define HD 64
#define MROWS (B * S)          // 4096
#define NELEM (B * S * D)      // 3145728

typedef __attribute__((ext_vector_type(8))) short short8;
typedef __attribute__((ext_vector_type(4))) short s16x4;
typedef __attribute__((ext_vector_type(4))) float f32x4;

#define MFMA16(a, b, c) __builtin_amdgcn_mfma_f32_16x16x32_bf16(a, b, c, 0, 0, 0)

// LDS XOR-swizzles (col in shorts, 8-short granular, bijective per row)
#define SWZ64(row, col)  ((col) ^ (((row) & 7) << 3))        // 64-short (128B) rows
#define SWZ128(row, col) ((col) ^ (((row) & 15) << 3))       // 128-short (256B) rows

static __device__ __forceinline__ float bs2f(short s) {
    unsigned int u = ((unsigned int)(unsigned short)s) << 16;
    float f;
    __builtin_memcpy(&f, &u, 4);
    return f;
}
static __device__ __forceinline__ short f2bs(float f) {
    __hip_bfloat16 h = __float2bfloat16(f);
    return __builtin_bit_cast(short, h);
}
// HW packed fp32->bf16 (RNE, single VALU op)
static __device__ __forceinline__ unsigned int cvtpk_bf16(float lo, float hi) {
    unsigned int r;
    asm("v_cvt_pk_bf16_f32 %0, %1, %2" : "=v"(r) : "v"(lo), "v"(hi));
    return r;
}
static __device__ __forceinline__ float fmax3(float a, float b, float c) {
    float r;
    asm("v_max3_f32 %0, %1, %2, %3" : "=v"(r) : "v"(a), "v"(b), "v"(c));
    return r;
}
static __device__ __forceinline__ float loadin(const void* p, size_t i, int isb) {
    return isb ? bs2f(((const short*)p)[i]) : ((const float*)p)[i];
}

// ======================= dtype detect (wave-parallel) =======================
__global__ void detect_k(const void* p, int* flag) {
    const short* hb = (const short*)p;
    int t = threadIdx.x;     // 64
    int ins = 0;
    #pragma unroll
    for (int j = 0; j < 4; j++) {
        float v = bs2f(hb[(t * 4 + j) * 2]);
        if (!(v == v) || fabsf(v) > 1e3f || (v != 0.0f && fabsf(v) < 1e-20f)) ins++;
    }
    #pragma unroll
    for (int off = 32; off; off >>= 1) ins += __shfl_xor(ins, off);
    if (t == 0) *flag = (ins > 64) ? 0 : 1;
}

// ======================= embed + positional (dual fp32 + bf16) =======================
__global__ __launch_bounds__(256) void embed_pos_k(const int* __restrict__ x,
                                                   const void* __restrict__ embed,
                                                   float* __restrict__ outf,
                                                   short* __restrict__ outb,
                                                   const int* __restrict__ flg) {
    const int f = *flg;
    int bs = blockIdx.x;
    int tok = x[bs];
    int s = bs & (S - 1);
    for (int j = threadIdx.x; j < D; j += 256) {
        float e = loadin(embed, (size_t)tok * D + j, f);
        int i = j >> 1;
        float ang = (float)s * __expf(-9.210340371976184f * (2.0f * (float)i) / (float)D);
        float p = (j & 1) ? cosf(ang) : sinf(ang);
        float v = 2.0f * e + p;
        outf[bs * D + j] = v;
        outb[bs * D + j] = f2bs(v);
    }
}

// ======================= fused prep: 8x weight transpose + encod convert + sums zero =======================
struct WSegs {
    const void* src[8];
    short* dst[8];
    int K[8];
    const void* esrc;
    short* edst;
    float* statz;          // 6 sums buffers to zero (9216 floats)
};

__global__ __launch_bounds__(256) void prep_k(WSegs sg, const int* __restrict__ flg) {
    const int f = *flg;
    const int seg = blockIdx.z;
    const int t = threadIdx.x;
    if (seg == 8) {
        int tid = (blockIdx.y * 12 + blockIdx.x) * 256 + t;
        if (tid < 9216) sg.statz[tid] = 0.f;
        for (int i = tid; i < NELEM; i += 12 * 12 * 256)
            sg.edst[i] = f2bs(loadin(sg.esrc, i, f));
        return;
    }
    const int K = sg.K[seg];
    const int k0 = blockIdx.y * 64;
    if (k0 >= K) return;
    const void* src = sg.src[seg];
    short* dst = sg.dst[seg];
    __shared__ __align__(16) short Ts[64 * 72];
    int n0 = blockIdx.x * 64;
    int r = t >> 2, c4 = (t & 3) * 16;
    #pragma unroll
    for (int j = 0; j < 16; j++)
        Ts[r * 72 + c4 + j] = f2bs(loadin(src, (size_t)(k0 + r) * D + n0 + c4 + j, f));
    __syncthreads();
    int n = t >> 2, kc = (t & 3) * 16;
    short tmp[16];
    #pragma unroll
    for (int j = 0; j < 16; j++) tmp[j] = Ts[(kc + j) * 72 + n];
    short* dchunk = dst + (size_t)(n0 + n) * K + k0 + kc;
    *(short8*)&dchunk[0] = *(const short8*)&tmp[0];
    *(short8*)&dchunk[8] = *(const short8*)&tmp[8];
}

// final store with inline BN (per-element finalize from sums)
__global__ __launch_bounds__(256) void store_norm_k(const float* __restrict__ a,
                                                    const float* __restrict__ sums,
                                                    const void* __restrict__ g,
                                                    const void* __restrict__ beta,
                                                    void* __restrict__ out,
                                                    const int* __restrict__ flg) {
    const int f = *flg;
    int i = blockIdx.x * 256 + threadIdx.x;
    if (i < NELEM) {
        int ft = i % D;
        float mean = sums[ft] * (1.0f / (float)MROWS);
        float var = sums[D + ft] * (1.0f / (float)MROWS) - mean * mean;
        float sc = rsqrtf(var + 1e-5f) * loadin(g, ft, f);
        float y = (a[i] - mean) * sc + loadin(beta, ft, f);
        if (f) ((short*)out)[i] = f2bs(y);
        else   ((float*)out)[i] = y;
    }
}

// ======================= MFMA GEMM: 64x64 tile, BK=64 double-buffered, XCD-swizzled, inline-BN =======================
// modes: 0=flat bf16, 1=head bf16, 2=flat fp32 (+resid, +stats), 3=per-head transposed bf16
struct GJob {
    const void* A;
    const short* WT;
    const void* bias;
    void* out;
    const float* resid;
    const float* bnsums;
    const void* bng;
    const void* bnb;
    float* sacc;
    int K;
    int aoff;
    int relu;
    int mode;
    int anorm;
    int rnorm;
};
struct GJobs { GJob j[3]; };

__global__ __launch_bounds__(256) void mgemm_k(GJobs js, const int* __restrict__ flg) {
    const GJob J = js.j[blockIdx.z];
    const int f = *flg;
    __shared__ __align__(16) short As[2][64 * 64];
    __shared__ __align__(16) short Bs[2][64 * 64];
    __shared__ float ssb0[768];
    __shared__ float ssb1[768];
    const int t = threadIdx.x;
    const int wave = t >> 6, lane = t & 63;
    const int quad = lane >> 4, l16 = lane & 15;
    if (J.anorm) {
        for (int i = t; i < D; i += 256) {
            float mean = J.bnsums[i] * (1.0f / (float)MROWS);
            float var = J.bnsums[D + i] * (1.0f / (float)MROWS) - mean * mean;
            float sc = rsqrtf(var + 1e-5f) * loadin(J.bng, i, f);
            ssb0[i] = sc;
            ssb1[i] = loadin(J.bnb, i, f) - mean * sc;
        }
        __syncthreads();
    }
    // XCD-aware bijective swizzle (nwg = 768 = 8*96)
    int lin = blockIdx.y * gridDim.x + blockIdx.x;
    int per = (gridDim.x * gridDim.y) >> 3;
    int nl = (lin & 7) * per + (lin >> 3);
    const int n0 = (nl % gridDim.x) * 64;
    const int m0 = (nl / gridDim.x) * 64;
    const int wm = (wave >> 1) * 32;
    const int wn = (wave & 1) * 32;
    f32x4 acc[2][2];
    #pragma unroll
    for (int i = 0; i < 2; i++)
        #pragma unroll
        for (int j = 0; j < 2; j++) acc[i][j] = f32x4{0.f, 0.f, 0.f, 0.f};

    const int ar = t >> 2;             // 0..63
    const int ac = (t & 3) * 16;       // 0,16,32,48
    const int wsz0 = SWZ64(ar, ac);
    const int wsz1 = SWZ64(ar, ac + 8);
    const int K = J.K;

    auto stageA = [&](int k0, short8& r0, short8& r1) {
        if (J.anorm) {
            int ft = J.aoff + k0 + ac;
            const float* Af = (const float*)J.A + (size_t)(m0 + ar) * 768 + ft;
            f32x4 v0 = *(const f32x4*)&Af[0];
            f32x4 v1 = *(const f32x4*)&Af[4];
            f32x4 v2 = *(const f32x4*)&Af[8];
            f32x4 v3 = *(const f32x4*)&Af[12];
            f32x4 c0 = *(const f32x4*)&ssb0[ft];
            f32x4 c1 = *(const f32x4*)&ssb0[ft + 4];
            f32x4 c2 = *(const f32x4*)&ssb0[ft + 8];
            f32x4 c3 = *(const f32x4*)&ssb0[ft + 12];
            f32x4 h0 = *(const f32x4*)&ssb1[ft];
            f32x4 h1 = *(const f32x4*)&ssb1[ft + 4];
            f32x4 h2 = *(const f32x4*)&ssb1[ft + 8];
            f32x4 h3 = *(const f32x4*)&ssb1[ft + 12];
            union { unsigned int u[4]; short8 s; } ca, cb;
            ca.u[0] = cvtpk_bf16(v0[0] * c0[0] + h0[0], v0[1] * c0[1] + h0[1]);
            ca.u[1] = cvtpk_bf16(v0[2] * c0[2] + h0[2], v0[3] * c0[3] + h0[3]);
            ca.u[2] = cvtpk_bf16(v1[0] * c1[0] + h1[0], v1[1] * c1[1] + h1[1]);
            ca.u[3] = cvtpk_bf16(v1[2] * c1[2] + h1[2], v1[3] * c1[3] + h1[3]);
            cb.u[0] = cvtpk_bf16(v2[0] * c2[0] + h2[0], v2[1] * c2[1] + h2[1]);
            cb.u[1] = cvtpk_bf16(v2[2] * c2[2] + h2[2], v2[3] * c2[3] + h2[3]);
            cb.u[2] = cvtpk_bf16(v3[0] * c3[0] + h3[0], v3[1] * c3[1] + h3[1]);
            cb.u[3] = cvtpk_bf16(v3[2] * c3[2] + h3[2], v3[3] * c3[3] + h3[3]);
            r0 = ca.s;
            r1 = cb.s;
        } else {
            const short* Ab = (const short*)J.A + (size_t)(m0 + ar) * 768 + k0 + ac;
            r0 = *(const short8*)&Ab[0];
            r1 = *(const short8*)&Ab[8];
        }
    };

    // prologue: stage step 0 into buffer 0
    {
        short8 a0, a1, b0, b1;
        stageA(0, a0, a1);
        const short* Wb = &J.WT[(size_t)(n0 + ar) * K + ac];
        b0 = *(const short8*)&Wb[0];
        b1 = *(const short8*)&Wb[8];
        *(short8*)&As[0][ar * 64 + wsz0] = a0;
        *(short8*)&As[0][ar * 64 + wsz1] = a1;
        *(short8*)&Bs[0][ar * 64 + wsz0] = b0;
        *(short8*)&Bs[0][ar * 64 + wsz1] = b1;
    }
    __syncthreads();

    int cur = 0;
    for (int k0 = 0; k0 < K; k0 += 64) {
        short8 na0, na1, nb0, nb1;
        const bool more = (k0 + 64 < K);
        if (more) {
            stageA(k0 + 64, na0, na1);
            const short* Wb = &J.WT[(size_t)(n0 + ar) * K + k0 + 64 + ac];
            nb0 = *(const short8*)&Wb[0];
            nb1 = *(const short8*)&Wb[8];
        }
        #pragma unroll
        for (int kk = 0; kk < 2; kk++) {
            short8 af[2], bfr[2];
            #pragma unroll
            for (int i = 0; i < 2; i++) {
                int arow = wm + i * 16 + l16;
                af[i] = *(const short8*)&As[cur][arow * 64 + SWZ64(arow, kk * 32 + quad * 8)];
            }
            #pragma unroll
            for (int j = 0; j < 2; j++) {
                int brow = wn + j * 16 + l16;
                bfr[j] = *(const short8*)&Bs[cur][brow * 64 + SWZ64(brow, kk * 32 + quad * 8)];
            }
            #pragma unroll
            for (int i = 0; i < 2; i++)
                #pragma unroll
                for (int j = 0; j < 2; j++)
                    acc[i][j] = MFMA16(af[i], bfr[j], acc[i][j]);
        }
        if (more) {
            *(short8*)&As[cur ^ 1][ar * 64 + wsz0] = na0;
            *(short8*)&As[cur ^ 1][ar * 64 + wsz1] = na1;
            *(short8*)&Bs[cur ^ 1][ar * 64 + wsz0] = nb0;
            *(short8*)&Bs[cur ^ 1][ar * 64 + wsz1] = nb1;
        }
        __syncthreads();
        cur ^= 1;
    }

    if (J.mode == 3) {
        // stage bias+relu'd tile transposed into LDS (reuse As as scratch, pad 72)
        short* sb = &As[0][0];
        #pragma unroll
        for (int j = 0; j < 2; j++) {
            int coll = wn + j * 16 + l16;
            float bv = loadin(J.bias, n0 + coll, f);
            #pragma unroll
            for (int i = 0; i < 2; i++) {
                int rowl = wm + i * 16 + quad * 4;
                float e0 = acc[i][j][0] + bv, e1 = acc[i][j][1] + bv;
                float e2 = acc[i][j][2] + bv, e3 = acc[i][j][3] + bv;
                if (J.relu) {
                    e0 = fmaxf(e0, 0.f); e1 = fmaxf(e1, 0.f);
                    e2 = fmaxf(e2, 0.f); e3 = fmaxf(e3, 0.f);
                }
                union { unsigned int u[2]; s16x4 s; } cv;
                cv.u[0] = cvtpk_bf16(e0, e1);
                cv.u[1] = cvtpk_bf16(e2, e3);
                *(s16x4*)&sb[coll * 72 + rowl] = cv.s;
            }
        }
        __syncthreads();
        int hd = t >> 2, c = (t & 3) * 16;
        int b = m0 >> 10, s0 = m0 & (S - 1), h = n0 >> 6;
        short* dst = (short*)J.out + (((size_t)(b * H + h) * HD + hd) * S + s0 + c);
        *(short8*)&dst[0] = *(const short8*)&sb[hd * 72 + c];
        *(short8*)&dst[8] = *(const short8*)&sb[hd * 72 + c + 8];
    } else {
        #pragma unroll
        for (int j = 0; j < 2; j++) {
            int col = n0 + wn + j * 16 + l16;
            float bv = loadin(J.bias, col, f);
            float rsc = 1.f, rsh = 0.f;
            if (J.rnorm) {
                float mean = J.bnsums[col] * (1.0f / (float)MROWS);
                float var = J.bnsums[D + col] * (1.0f / (float)MROWS) - mean * mean;
                rsc = rsqrtf(var + 1e-5f) * loadin(J.bng, col, f);
                rsh = loadin(J.bnb, col, f) - mean * rsc;
            }
            float s1 = 0.f, s2 = 0.f;
            #pragma unroll
            for (int i = 0; i < 2; i++) {
                int rowb = m0 + wm + i * 16 + quad * 4;
                #pragma unroll
                for (int r = 0; r < 4; r++) {
                    float v = acc[i][j][r] + bv;
                    if (J.relu) v = fmaxf(v, 0.f);
                    int row = rowb + r;
                    if (J.mode == 2) {
                        size_t idx = (size_t)row * D + col;
                        if (J.resid) {
                            float rv = J.resid[idx];
                            v += J.rnorm ? (rv * rsc + rsh) : rv;
                        }
                        ((float*)J.out)[idx] = v;
                        s1 += v;
                        s2 += v * v;
                    } else if (J.mode == 1) {
                        size_t idx = (((size_t)(row >> 10) * H + (col >> 6)) * S + (row & (S - 1))) * HD + (col & 63);
                        ((short*)J.out)[idx] = f2bs(v);
                    } else {
                        ((short*)J.out)[(size_t)row * D + col] = f2bs(v);
                    }
                }
            }
            if (J.mode == 2 && J.sacc) {
                s1 += __shfl_xor(s1, 16); s1 += __shfl_xor(s1, 32);
                s2 += __shfl_xor(s2, 16); s2 += __shfl_xor(s2, 32);
                if (quad == 0) {
                    atomicAdd(&J.sacc[col], s1);
                    atomicAdd(&J.sacc[D + col], s2);
                }
            }
        }
    }
}

// ======================= MFMA flash attention: swapped QK^T, KVBLK=128, 8 waves / 128 q-rows =======================
// K/V tile staged once serves 8 waves (2x amortization vs 4-wave); per-wave math identical.
// grid: (B*H, S/128) — bh fastest so all q-tiles of one head share an XCD (K/V L2-resident)
__global__ __launch_bounds__(512) void mfma_attn_fo_k(const short* __restrict__ Q,
                                                      const short* __restrict__ Km,
                                                      const short* __restrict__ Vt,
                                                      void* __restrict__ out,
                                                      const float* __restrict__ resid,
                                                      const float* __restrict__ rsums,
                                                      const void* __restrict__ rg,
                                                      const void* __restrict__ rb,
                                                      float* __restrict__ sacc,
                                                      float scale, int obf,
                                                      const int* __restrict__ flg) {
    __shared__ __align__(16) short Ks[128 * 64];
    __shared__ __align__(16) short Vs[64 * 128];
    __shared__ __align__(16) short Ps[8][16 * 136];
    const int fl = *flg;
    const int qt = blockIdx.y;
    const int bh = blockIdx.x;
    const int b = bh / H, h = bh % H;
    const int t = threadIdx.x;
    const int wave = t >> 6, lane = t & 63, quad = lane >> 4, l16 = lane & 15;
    const float sc2 = scale * 1.44269504089f;     // scale folded into exp2 arg
    const short* Qh = Q + (size_t)bh * S * HD;
    const short* Kh = Km + (size_t)bh * S * HD;
    const short* Vh = Vt + (size_t)bh * S * HD;
    const int qrow = qt * 128 + wave * 16 + l16;
    short8 qf0 = *(const short8*)&Qh[(size_t)qrow * 64 + quad * 8];
    short8 qf1 = *(const short8*)&Qh[(size_t)qrow * 64 + 32 + quad * 8];
    short8 ones;
    #pragma unroll
    for (int j = 0; j < 8; j++) ones[j] = (short)0x3F80;   // bf16 1.0
    f32x4 o[4];
    f32x4 ls = f32x4{0.f, 0.f, 0.f, 0.f};
    float m_i = -1e30f;                            // running max for q = wave*16 + l16
    #pragma unroll
    for (int nt = 0; nt < 4; nt++) o[nt] = f32x4{0.f, 0.f, 0.f, 0.f};
    // staging split across 512 threads: 16 shorts each for K and V
    const int krow = t >> 2, kc0 = (t & 3) * 16;   // K tile: 128 rows x 64
    const int vhd = t >> 3, vkc = (t & 7) * 16;    // V tile: 64 rows x 128
    const short* kbase = &Kh[(size_t)krow * 64 + kc0];
    const short* vbase = &Vh[(size_t)vhd * S + vkc];

    short8 kreg[2], vreg[2];
    // prologue: stage tile 0
    #pragma unroll
    for (int j = 0; j < 2; j++) kreg[j] = *(const short8*)&kbase[j * 8];
    #pragma unroll
    for (int j = 0; j < 2; j++) vreg[j] = *(const short8*)&vbase[j * 8];
    #pragma unroll
    for (int j = 0; j < 2; j++)
        *(short8*)&Ks[krow * 64 + SWZ64(krow, kc0 + j * 8)] = kreg[j];
    #pragma unroll
    for (int j = 0; j < 2; j++)
        *(short8*)&Vs[vhd * 128 + SWZ128(vhd, vkc + j * 8)] = vreg[j];
    __syncthreads();

    for (int kt = 0; kt < S; kt += 128) {
        // issue next-tile loads early (latency hides under QK^T/softmax/PV)
        if (kt + 128 < S) {
            #pragma unroll
            for (int j = 0; j < 2; j++)
                kreg[j] = *(const short8*)&kbase[(size_t)(kt + 128) * 64 + j * 8];
            #pragma unroll
            for (int j = 0; j < 2; j++)
                vreg[j] = *(const short8*)&vbase[kt + 128 + j * 8];
        }
        // swapped QK^T: D = K·Q^T = S^T.  sf[nt][r] holds (k = nt*16+quad*4+r, q = l16)
        f32x4 sf[8];
        #pragma unroll
        for (int nt = 0; nt < 8; nt++) {
            int kr = nt * 16 + l16;
            short8 kb0 = *(const short8*)&Ks[kr * 64 + SWZ64(kr, quad * 8)];
            short8 kb1 = *(const short8*)&Ks[kr * 64 + SWZ64(kr, 32 + quad * 8)];
            f32x4 c = f32x4{0.f, 0.f, 0.f, 0.f};
            c = MFMA16(kb0, qf0, c);
            c = MFMA16(kb1, qf1, c);
            sf[nt] = c;      // raw scores
        }
        // in-lane max tree via v_max3 (32 values, one q per lane) + 2 cross-quad shuffles
        float mr[4];
        #pragma unroll
        for (int r = 0; r < 4; r++) {
            float a = fmax3(sf[0][r], sf[1][r], sf[2][r]);
            float bm = fmax3(sf[3][r], sf[4][r], sf[5][r]);
            float c = fmaxf(sf[6][r], sf[7][r]);
            mr[r] = fmax3(a, bm, c);
        }
        float mx = fmaxf(fmax3(mr[0], mr[1], mr[2]), mr[3]);
        mx = fmaxf(mx, __shfl_xor(mx, 16));
        mx = fmaxf(mx, __shfl_xor(mx, 32));
        // defer-max: rescale only if this row's max grew past threshold
        bool need = ((mx - m_i) * sc2 > 8.0f);
        if (__any(need)) {
            float mnew = fmaxf(m_i, mx);
            float alpha = exp2f((m_i - mnew) * sc2);
            m_i = mnew;
            #pragma unroll
            for (int r = 0; r < 4; r++) {
                float ar = __shfl(alpha, quad * 4 + r);   // alpha for q = quad*4+r
                ls[r] *= ar;
                #pragma unroll
                for (int nt = 0; nt < 4; nt++) o[nt][r] *= ar;
            }
        }
        // P pack: exp2 + HW packed cvt, one uint2 (b64) write per nt
        #pragma unroll
        for (int nt = 0; nt < 8; nt++) {
            float e0 = exp2f((sf[nt][0] - m_i) * sc2);
            float e1 = exp2f((sf[nt][1] - m_i) * sc2);
            float e2 = exp2f((sf[nt][2] - m_i) * sc2);
            float e3 = exp2f((sf[nt][3] - m_i) * sc2);
            unsigned int w0 = cvtpk_bf16(e0, e1);
            unsigned int w1 = cvtpk_bf16(e2, e3);
            *(uint2*)&Ps[wave][l16 * 136 + nt * 16 + quad * 4] = make_uint2(w0, w1);
        }
        short8 pa[4];
        #pragma unroll
        for (int kc = 0; kc < 4; kc++)
            pa[kc] = *(const short8*)&Ps[wave][l16 * 136 + kc * 32 + quad * 8];
        #pragma unroll
        for (int nt = 0; nt < 4; nt++) {
            int vr = nt * 16 + l16;
            #pragma unroll
            for (int kc = 0; kc < 4; kc++) {
                short8 vb = *(const short8*)&Vs[vr * 128 + SWZ128(vr, kc * 32 + quad * 8)];
                o[nt] = MFMA16(pa[kc], vb, o[nt]);
            }
        }
        // softmax denominator via MFMA: ls += P . 1  (ls[r] is q = quad*4+r, matches o)
        #pragma unroll
        for (int kc = 0; kc < 4; kc++) ls = MFMA16(pa[kc], ones, ls);
        __syncthreads();   // all waves done reading Ks/Vs
        if (kt + 128 < S) {
            #pragma unroll
            for (int j = 0; j < 2; j++)
                *(short8*)&Ks[krow * 64 + SWZ64(krow, kc0 + j * 8)] = kreg[j];
            #pragma unroll
            for (int j = 0; j < 2; j++)
                *(short8*)&Vs[vhd * 128 + SWZ128(vhd, vkc + j * 8)] = vreg[j];
        }
        __syncthreads();   // next tile visible
    }
    float inv[4];
    #pragma unroll
    for (int r = 0; r < 4; r++) inv[r] = 1.0f / ls[r];
    #pragma unroll
    for (int nt = 0; nt < 4; nt++) {
        int col = h * HD + nt * 16 + l16;
        float rsc = 1.f, rsh = 0.f;
        if (rsums) {
            float mean = rsums[col] * (1.0f / (float)MROWS);
            float var = rsums[D + col] * (1.0f / (float)MROWS) - mean * mean;
            rsc = rsqrtf(var + 1e-5f) * loadin(rg, col, fl);
            rsh = loadin(rb, col, fl) - mean * rsc;
        }
        float s1 = 0.f, s2 = 0.f;
        #pragma unroll
        for (int r = 0; r < 4; r++) {
            int row = b * S + qt * 128 + wave * 16 + quad * 4 + r;
            size_t idx = (size_t)row * D + col;
            float v = o[nt][r] * inv[r];
            if (obf) {
                ((short*)out)[idx] = f2bs(v);
            } else {
                if (resid) {
                    float rv = resid[idx];
                    v += rsums ? (rv * rsc + rsh) : rv;
                }
                ((float*)out)[idx] = v;
                s1 += v;
                s2 += v * v;
            }
        }
        if (sacc) {
            s1 += __shfl_xor(s1, 16); s1 += __shfl_xor(s1, 32);
            s2 += __shfl_xor(s2, 16); s2 += __shfl_xor(s2, 32);
            if (quad == 0) {
                atomicAdd(&sacc[col], s1);
                atomicAdd(&sacc[D + col], s2);
            }
        }
    }
}

extern "C" void kernel_launch(void* const* d_in, const int* in_sizes, int n_in,
                              void* d_out, int out_size, void* d_ws, size_t ws_size,
                              hipStream_t stream) {
    const int* x = (const int*)d_in[0];
    const short* encod = (const short*)d_in[1];
    const short* embed = (const short*)d_in[2];
    const short* Wq = (const short*)d_in[3];
    const short* bq = (const short*)d_in[4];
    const short* Wk = (const short*)d_in[5];
    const short* bk = (const short*)d_in[6];
    const short* Wv = (const short*)d_in[7];
    const short* bv = (const short*)d_in[8];
    const short* g1 = (const short*)d_in[9];
    const short* b1 = (const short*)d_in[10];
    const short* Wq2 = (const short*)d_in[11];
    const short* bq2 = (const short*)d_in[12];
    const short* Wk2 = (const short*)d_in[13];
    const short* bk2 = (const short*)d_in[14];
    const short* Wv2 = (const short*)d_in[15];
    const short* bv2 = (const short*)d_in[16];
    const short* Wo2 = (const short*)d_in[17];
    const short* bo2 = (const short*)d_in[18];
    const short* g2 = (const short*)d_in[19];
    const short* b2 = (const short*)d_in[20];
    const short* Wf = (const short*)d_in[21];
    const short* bf_ = (const short*)d_in[22];

    // ---- workspace layout in half-BUF (hb = NELEM shorts) units ----
    short* HBase = (short*)d_ws;
    #define HB(i) (HBase + (size_t)(i) * NELEM)
    float* IMf = (float*)HB(0);        // hb0-1  fp32 input_multi (iter0 resid)
    short* IMb = HB(2);                // hb2    bf16 operand copy (iter0 self-proj A)
    short* Q2h = HB(3);                // hb3    persistent cross Q (bf16 head layout)
    short* K2h = HB(4);                // hb4    persistent cross K
    short* WTp = HB(5);                // hb5    packed transposed bf16 weights
    short* WTq  = WTp;                 // [768][256]
    short* WTk  = WTp + 196608;
    short* WTv  = WTp + 393216;
    short* WTq2 = WTp + 589824;        // [768][384]
    short* WTk2 = WTp + 884736;
    short* WTv2 = WTp + 1179648;       // [768][768]
    short* WTo2 = WTp + 1769472;
    short* WTf  = WTp + 2359296;
    short* Qbh = HB(6);                // hb6    self Q (bf16 head); Eb pre-loop
    short* Kbh = HB(7);                // hb7    self K
    short* Vth = HB(9);                // hb9    V transposed [B,H,64,S]
    float* T1f = (float*)HB(10);       // hb10-11 raw BN1 input (IM+sa)
    float* Ff  = (float*)HB(12);       // hb12-13 raw BN3 input (t2+ffn)
    short* A2b = HB(15);               // hb15   cross-attn out bf16
    float* T2f = (float*)HB(16);       // hb16-17 raw BN2 input (m2+t)
    short* Eb  = Qbh;                  // pre-loop: encod bf16
    float* SU = (float*)HB(18);        // 6 sums buffers
    #define SUMS(it, bn) (SU + (size_t)((it) * 3 + (bn)) * 2 * D)
    int*   flg  = (int*)(SU + 12 * D);

    const dim3 gGrid(12, 64);                // 768 blocks = 3/CU
    const dim3 aGrid(B * H, S / 128);        // (48, 8) — bh fastest -> XCD-local K/V
    const int EB = (NELEM + 255) / 256;
    const float scale1 = 0.03608439182435161f;   // 1/sqrt(768)
    const float scale2 = 0.125f;                 // 1/sqrt(64)

    detect_k<<<1, 64, 0, stream>>>(encod, flg);
    embed_pos_k<<<MROWS, 256, 0, stream>>>(x, embed, IMf, IMb, flg);

    // fused: 8 weight transposes + encod convert + sums zero (one dispatch)
    WSegs sg;
    sg.src[0] = Wq;  sg.dst[0] = WTq;  sg.K[0] = 256;
    sg.src[1] = Wk;  sg.dst[1] = WTk;  sg.K[1] = 256;
    sg.src[2] = Wv;  sg.dst[2] = WTv;  sg.K[2] = 256;
    sg.src[3] = Wq2; sg.dst[3] = WTq2; sg.K[3] = 384;
    sg.src[4] = Wk2; sg.dst[4] = WTk2; sg.K[4] = 384;
    sg.src[5] = Wv2; sg.dst[5] = WTv2; sg.K[5] = 768;
    sg.src[6] = Wo2; sg.dst[6] = WTo2; sg.K[6] = 768;
    sg.src[7] = Wf;  sg.dst[7] = WTf;  sg.K[7] = 768;
    sg.esrc = encod; sg.edst = Eb; sg.statz = SU;
    prep_k<<<dim3(12, 12, 9), 256, 0, stream>>>(sg, flg);

    // cross-attn Q/K projections (persistent, bf16 head layout) — merged z=2
    {
        GJobs js;
        js.j[0] = GJob{Eb,       WTq2, bq2, Q2h, nullptr, nullptr, nullptr, nullptr, nullptr, 384, 0, 0, 1, 0, 0};
        js.j[1] = GJob{Eb + 384, WTk2, bk2, K2h, nullptr, nullptr, nullptr, nullptr, nullptr, 384, 0, 0, 1, 0, 0};
        js.j[2] = js.j[0];
        mgemm_k<<<dim3(12, 64, 2), 256, 0, stream>>>(js, flg);
    }

    for (int it = 0; it < 2; it++) {
        // self-attn projections: Q,K head layout; V directly transposed (merged z=3)
        {
            GJobs js;
            if (it == 0) {
                js.j[0] = GJob{IMb,       WTq, bq, Qbh, nullptr, nullptr, nullptr, nullptr, nullptr, 256, 0,   1, 1, 0, 0};
                js.j[1] = GJob{IMb + 256, WTk, bk, Kbh, nullptr, nullptr, nullptr, nullptr, nullptr, 256, 0,   1, 1, 0, 0};
                js.j[2] = GJob{IMb + 512, WTv, bv, Vth, nullptr, nullptr, nullptr, nullptr, nullptr, 256, 0,   1, 3, 0, 0};
            } else {
                js.j[0] = GJob{Ff, WTq, bq, Qbh, nullptr, SUMS(0, 2), g2, b2, nullptr, 256, 0,   1, 1, 1, 0};
                js.j[1] = GJob{Ff, WTk, bk, Kbh, nullptr, SUMS(0, 2), g2, b2, nullptr, 256, 256, 1, 1, 1, 0};
                js.j[2] = GJob{Ff, WTv, bv, Vth, nullptr, SUMS(0, 2), g2, b2, nullptr, 256, 512, 1, 3, 1, 0};
            }
            mgemm_k<<<dim3(12, 64, 3), 256, 0, stream>>>(js, flg);
        }
        // T1f = resid + sa  (BN1 sums accumulated)
        if (it == 0)
            mfma_attn_fo_k<<<aGrid, 512, 0, stream>>>(Qbh, Kbh, Vth, T1f, IMf,
                    nullptr, nullptr, nullptr, SUMS(0, 0), scale1, 0, flg);
        else
            mfma_attn_fo_k<<<aGrid, 512, 0, stream>>>(Qbh, Kbh, Vth, T1f, Ff,
                    SUMS(0, 2), g2, b2, SUMS(1, 0), scale1, 0, flg);
        // V2 = bn1(T1f) @ Wv2 -> transposed into Vth
        {
            GJobs js;
            js.j[0] = GJob{T1f, WTv2, bv2, Vth, nullptr, SUMS(it, 0), g1, b1, nullptr, 768, 0, 0, 3, 1, 0};
            js.j[1] = js.j[0]; js.j[2] = js.j[0];
            mgemm_k<<<gGrid, 256, 0, stream>>>(js, flg);
        }
        mfma_attn_fo_k<<<aGrid, 512, 0, stream>>>(Q2h, K2h, Vth, A2b, nullptr,
                nullptr, nullptr, nullptr, nullptr, scale2, 1, flg);
        // T2f = attn2 @ Wo2 + bn1(T1f)  (BN2 sums accumulated)
        {
            GJobs js;
            js.j[0] = GJob{A2b, WTo2, bo2, T2f, T1f, SUMS(it, 0), g1, b1, SUMS(it, 1), 768, 0, 0, 2, 0, 1};
            js.j[1] = js.j[0]; js.j[2] = js.j[0];
            mgemm_k<<<gGrid, 256, 0, stream>>>(js, flg);
        }
        // Ff = bn2(T2f) @ Wf + bn2(T2f)  (BN3 sums accumulated)
        {
            GJobs js;
            js.j[0] = GJob{T2f, WTf, bf_, Ff, T2f, SUMS(it, 1), g2, b2, SUMS(it, 2), 768, 0, 0, 2, 1, 1};
            js.j[1] = js.j[0]; js.j[2] = js.j[0];
            mgemm_k<<<gGrid, 256, 0, stream>>>(js, flg);
        }
    }

    store_norm_k<<<EB, 256, 0, stream>>>(Ff, SUMS(1, 2), g2, b2, d_out, flg);
}

// Round 13
// 541.589 us; speedup vs baseline: 1.0639x; 1.0639x over previous
//
#include <hip/hip_runtime.h>
#include <hip/hip_bf16.h>

#define B 4
#define S 1024
#define D 768
#define H 12
#define HD 64
#define MROWS (B * S)          // 4096
#define NELEM (B * S * D)      // 3145728

typedef __attribute__((ext_vector_type(8))) short short8;
typedef __attribute__((ext_vector_type(4))) short s16x4;
typedef __attribute__((ext_vector_type(4))) float f32x4;

#define MFMA16(a, b, c) __builtin_amdgcn_mfma_f32_16x16x32_bf16(a, b, c, 0, 0, 0)

// LDS XOR-swizzles (col in shorts, 8-short granular, bijective per row)
#define SWZ64(row, col)  ((col) ^ (((row) & 7) << 3))        // 64-short (128B) rows
#define SWZ128(row, col) ((col) ^ (((row) & 15) << 3))       // 128-short (256B) rows

static __device__ __forceinline__ float bs2f(short s) {
    unsigned int u = ((unsigned int)(unsigned short)s) << 16;
    float f;
    __builtin_memcpy(&f, &u, 4);
    return f;
}
static __device__ __forceinline__ short f2bs(float f) {
    __hip_bfloat16 h = __float2bfloat16(f);
    return __builtin_bit_cast(short, h);
}
// HW packed fp32->bf16 (RNE, single VALU op)
static __device__ __forceinline__ unsigned int cvtpk_bf16(float lo, float hi) {
    unsigned int r;
    asm("v_cvt_pk_bf16_f32 %0, %1, %2" : "=v"(r) : "v"(lo), "v"(hi));
    return r;
}
static __device__ __forceinline__ float fmax3(float a, float b, float c) {
    float r;
    asm("v_max3_f32 %0, %1, %2, %3" : "=v"(r) : "v"(a), "v"(b), "v"(c));
    return r;
}
static __device__ __forceinline__ float loadin(const void* p, size_t i, int isb) {
    return isb ? bs2f(((const short*)p)[i]) : ((const float*)p)[i];
}

// ======================= dtype detect (wave-parallel) =======================
__global__ void detect_k(const void* p, int* flag) {
    const short* hb = (const short*)p;
    int t = threadIdx.x;     // 64
    int ins = 0;
    #pragma unroll
    for (int j = 0; j < 4; j++) {
        float v = bs2f(hb[(t * 4 + j) * 2]);
        if (!(v == v) || fabsf(v) > 1e3f || (v != 0.0f && fabsf(v) < 1e-20f)) ins++;
    }
    #pragma unroll
    for (int off = 32; off; off >>= 1) ins += __shfl_xor(ins, off);
    if (t == 0) *flag = (ins > 64) ? 0 : 1;
}

// ======================= embed + positional (dual fp32 + bf16) =======================
__global__ __launch_bounds__(256) void embed_pos_k(const int* __restrict__ x,
                                                   const void* __restrict__ embed,
                                                   float* __restrict__ outf,
                                                   short* __restrict__ outb,
                                                   const int* __restrict__ flg) {
    const int f = *flg;
    int bs = blockIdx.x;
    int tok = x[bs];
    int s = bs & (S - 1);
    for (int j = threadIdx.x; j < D; j += 256) {
        float e = loadin(embed, (size_t)tok * D + j, f);
        int i = j >> 1;
        float ang = (float)s * __expf(-9.210340371976184f * (2.0f * (float)i) / (float)D);
        float p = (j & 1) ? cosf(ang) : sinf(ang);
        float v = 2.0f * e + p;
        outf[bs * D + j] = v;
        outb[bs * D + j] = f2bs(v);
    }
}

// ======================= fused prep: 8x weight transpose + encod convert + sums zero =======================
struct WSegs {
    const void* src[8];
    short* dst[8];
    int K[8];
    const void* esrc;
    short* edst;
    float* statz;          // 6 sums buffers to zero (9216 floats)
};

__global__ __launch_bounds__(256) void prep_k(WSegs sg, const int* __restrict__ flg) {
    const int f = *flg;
    const int seg = blockIdx.z;
    const int t = threadIdx.x;
    if (seg == 8) {
        int tid = (blockIdx.y * 12 + blockIdx.x) * 256 + t;
        if (tid < 9216) sg.statz[tid] = 0.f;
        if (f) {
            // bf16 input: f2bs(bs2f(x)) == x -> pure vector copy
            const short* src = (const short*)sg.esrc;
            for (int i = tid * 8; i < NELEM; i += 12 * 12 * 256 * 8)
                *(short8*)&sg.edst[i] = *(const short8*)&src[i];
        } else {
            const float* src = (const float*)sg.esrc;
            for (int i = tid * 8; i < NELEM; i += 12 * 12 * 256 * 8) {
                f32x4 v0 = *(const f32x4*)&src[i];
                f32x4 v1 = *(const f32x4*)&src[i + 4];
                union { unsigned int u[4]; short8 s; } cv;
                cv.u[0] = cvtpk_bf16(v0[0], v0[1]);
                cv.u[1] = cvtpk_bf16(v0[2], v0[3]);
                cv.u[2] = cvtpk_bf16(v1[0], v1[1]);
                cv.u[3] = cvtpk_bf16(v1[2], v1[3]);
                *(short8*)&sg.edst[i] = cv.s;
            }
        }
        return;
    }
    const int K = sg.K[seg];
    const int k0 = blockIdx.y * 64;
    if (k0 >= K) return;
    const void* src = sg.src[seg];
    short* dst = sg.dst[seg];
    __shared__ __align__(16) short Ts[64 * 72];
    int n0 = blockIdx.x * 64;
    int r = t >> 2, c4 = (t & 3) * 16;
    #pragma unroll
    for (int j = 0; j < 16; j++)
        Ts[r * 72 + c4 + j] = f2bs(loadin(src, (size_t)(k0 + r) * D + n0 + c4 + j, f));
    __syncthreads();
    int n = t >> 2, kc = (t & 3) * 16;
    short tmp[16];
    #pragma unroll
    for (int j = 0; j < 16; j++) tmp[j] = Ts[(kc + j) * 72 + n];
    short* dchunk = dst + (size_t)(n0 + n) * K + k0 + kc;
    *(short8*)&dchunk[0] = *(const short8*)&tmp[0];
    *(short8*)&dchunk[8] = *(const short8*)&tmp[8];
}

// final store with inline BN, vectorized 4 elems/thread (4-aligned groups never cross a D row)
__global__ __launch_bounds__(256) void store_norm_k(const float* __restrict__ a,
                                                    const float* __restrict__ sums,
                                                    const void* __restrict__ g,
                                                    const void* __restrict__ beta,
                                                    void* __restrict__ out,
                                                    const int* __restrict__ flg) {
    const int f = *flg;
    int i = (blockIdx.x * 256 + threadIdx.x) * 4;
    if (i < NELEM) {
        int ft = i % D;
        f32x4 v = *(const f32x4*)&a[i];
        f32x4 sm = *(const f32x4*)&sums[ft];
        f32x4 sq = *(const f32x4*)&sums[D + ft];
        float y[4];
        #pragma unroll
        for (int e = 0; e < 4; e++) {
            float mean = sm[e] * (1.0f / (float)MROWS);
            float var = sq[e] * (1.0f / (float)MROWS) - mean * mean;
            float sc = rsqrtf(var + 1e-5f) * loadin(g, ft + e, f);
            y[e] = (v[e] - mean) * sc + loadin(beta, ft + e, f);
        }
        if (f) {
            uint2 pk = make_uint2(cvtpk_bf16(y[0], y[1]), cvtpk_bf16(y[2], y[3]));
            *(uint2*)&((short*)out)[i] = pk;
        } else {
            *(f32x4*)&((float*)out)[i] = f32x4{y[0], y[1], y[2], y[3]};
        }
    }
}

// ======================= MFMA GEMM: 64x64 tile, BK=64 double-buffered, XCD-swizzled, inline-BN =======================
// modes: 0=flat bf16, 1=head bf16, 2=flat fp32 (+resid, +stats), 3=per-head transposed bf16
struct GJob {
    const void* A;
    const short* WT;
    const void* bias;
    void* out;
    const float* resid;
    const float* bnsums;
    const void* bng;
    const void* bnb;
    float* sacc;
    int K;
    int aoff;
    int relu;
    int mode;
    int anorm;
    int rnorm;
};
struct GJobs { GJob j[3]; };

__global__ __launch_bounds__(256) void mgemm_k(GJobs js, const int* __restrict__ flg) {
    const GJob J = js.j[blockIdx.z];
    const int f = *flg;
    __shared__ __align__(16) short As[2][64 * 64];
    __shared__ __align__(16) short Bs[2][64 * 64];
    __shared__ float ssb0[768];
    __shared__ float ssb1[768];
    const int t = threadIdx.x;
    const int wave = t >> 6, lane = t & 63;
    const int quad = lane >> 4, l16 = lane & 15;
    if (J.anorm) {
        for (int i = t; i < D; i += 256) {
            float mean = J.bnsums[i] * (1.0f / (float)MROWS);
            float var = J.bnsums[D + i] * (1.0f / (float)MROWS) - mean * mean;
            float sc = rsqrtf(var + 1e-5f) * loadin(J.bng, i, f);
            ssb0[i] = sc;
            ssb1[i] = loadin(J.bnb, i, f) - mean * sc;
        }
        __syncthreads();
    }
    // XCD-aware bijective swizzle (nwg = 768 = 8*96)
    int lin = blockIdx.y * gridDim.x + blockIdx.x;
    int per = (gridDim.x * gridDim.y) >> 3;
    int nl = (lin & 7) * per + (lin >> 3);
    const int n0 = (nl % gridDim.x) * 64;
    const int m0 = (nl / gridDim.x) * 64;
    const int wm = (wave >> 1) * 32;
    const int wn = (wave & 1) * 32;
    f32x4 acc[2][2];
    #pragma unroll
    for (int i = 0; i < 2; i++)
        #pragma unroll
        for (int j = 0; j < 2; j++) acc[i][j] = f32x4{0.f, 0.f, 0.f, 0.f};

    const int ar = t >> 2;             // 0..63
    const int ac = (t & 3) * 16;       // 0,16,32,48
    const int wsz0 = SWZ64(ar, ac);
    const int wsz1 = SWZ64(ar, ac + 8);
    const int K = J.K;

    auto stageA = [&](int k0, short8& r0, short8& r1) {
        if (J.anorm) {
            int ft = J.aoff + k0 + ac;
            const float* Af = (const float*)J.A + (size_t)(m0 + ar) * 768 + ft;
            f32x4 v0 = *(const f32x4*)&Af[0];
            f32x4 v1 = *(const f32x4*)&Af[4];
            f32x4 v2 = *(const f32x4*)&Af[8];
            f32x4 v3 = *(const f32x4*)&Af[12];
            f32x4 c0 = *(const f32x4*)&ssb0[ft];
            f32x4 c1 = *(const f32x4*)&ssb0[ft + 4];
            f32x4 c2 = *(const f32x4*)&ssb0[ft + 8];
            f32x4 c3 = *(const f32x4*)&ssb0[ft + 12];
            f32x4 h0 = *(const f32x4*)&ssb1[ft];
            f32x4 h1 = *(const f32x4*)&ssb1[ft + 4];
            f32x4 h2 = *(const f32x4*)&ssb1[ft + 8];
            f32x4 h3 = *(const f32x4*)&ssb1[ft + 12];
            union { unsigned int u[4]; short8 s; } ca, cb;
            ca.u[0] = cvtpk_bf16(v0[0] * c0[0] + h0[0], v0[1] * c0[1] + h0[1]);
            ca.u[1] = cvtpk_bf16(v0[2] * c0[2] + h0[2], v0[3] * c0[3] + h0[3]);
            ca.u[2] = cvtpk_bf16(v1[0] * c1[0] + h1[0], v1[1] * c1[1] + h1[1]);
            ca.u[3] = cvtpk_bf16(v1[2] * c1[2] + h1[2], v1[3] * c1[3] + h1[3]);
            cb.u[0] = cvtpk_bf16(v2[0] * c2[0] + h2[0], v2[1] * c2[1] + h2[1]);
            cb.u[1] = cvtpk_bf16(v2[2] * c2[2] + h2[2], v2[3] * c2[3] + h2[3]);
            cb.u[2] = cvtpk_bf16(v3[0] * c3[0] + h3[0], v3[1] * c3[1] + h3[1]);
            cb.u[3] = cvtpk_bf16(v3[2] * c3[2] + h3[2], v3[3] * c3[3] + h3[3]);
            r0 = ca.s;
            r1 = cb.s;
        } else {
            const short* Ab = (const short*)J.A + (size_t)(m0 + ar) * 768 + k0 + ac;
            r0 = *(const short8*)&Ab[0];
            r1 = *(const short8*)&Ab[8];
        }
    };

    // prologue: stage step 0 into buffer 0
    {
        short8 a0, a1, b0, b1;
        stageA(0, a0, a1);
        const short* Wb = &J.WT[(size_t)(n0 + ar) * K + ac];
        b0 = *(const short8*)&Wb[0];
        b1 = *(const short8*)&Wb[8];
        *(short8*)&As[0][ar * 64 + wsz0] = a0;
        *(short8*)&As[0][ar * 64 + wsz1] = a1;
        *(short8*)&Bs[0][ar * 64 + wsz0] = b0;
        *(short8*)&Bs[0][ar * 64 + wsz1] = b1;
    }
    __syncthreads();

    int cur = 0;
    for (int k0 = 0; k0 < K; k0 += 64) {
        short8 na0, na1, nb0, nb1;
        const bool more = (k0 + 64 < K);
        if (more) {
            stageA(k0 + 64, na0, na1);
            const short* Wb = &J.WT[(size_t)(n0 + ar) * K + k0 + 64 + ac];
            nb0 = *(const short8*)&Wb[0];
            nb1 = *(const short8*)&Wb[8];
        }
        #pragma unroll
        for (int kk = 0; kk < 2; kk++) {
            short8 af[2], bfr[2];
            #pragma unroll
            for (int i = 0; i < 2; i++) {
                int arow = wm + i * 16 + l16;
                af[i] = *(const short8*)&As[cur][arow * 64 + SWZ64(arow, kk * 32 + quad * 8)];
            }
            #pragma unroll
            for (int j = 0; j < 2; j++) {
                int brow = wn + j * 16 + l16;
                bfr[j] = *(const short8*)&Bs[cur][brow * 64 + SWZ64(brow, kk * 32 + quad * 8)];
            }
            #pragma unroll
            for (int i = 0; i < 2; i++)
                #pragma unroll
                for (int j = 0; j < 2; j++)
                    acc[i][j] = MFMA16(af[i], bfr[j], acc[i][j]);
        }
        if (more) {
            *(short8*)&As[cur ^ 1][ar * 64 + wsz0] = na0;
            *(short8*)&As[cur ^ 1][ar * 64 + wsz1] = na1;
            *(short8*)&Bs[cur ^ 1][ar * 64 + wsz0] = nb0;
            *(short8*)&Bs[cur ^ 1][ar * 64 + wsz1] = nb1;
        }
        __syncthreads();
        cur ^= 1;
    }

    if (J.mode == 3) {
        // stage bias+relu'd tile transposed into LDS (reuse As as scratch, pad 72)
        short* sb = &As[0][0];
        #pragma unroll
        for (int j = 0; j < 2; j++) {
            int coll = wn + j * 16 + l16;
            float bv = loadin(J.bias, n0 + coll, f);
            #pragma unroll
            for (int i = 0; i < 2; i++) {
                int rowl = wm + i * 16 + quad * 4;
                float e0 = acc[i][j][0] + bv, e1 = acc[i][j][1] + bv;
                float e2 = acc[i][j][2] + bv, e3 = acc[i][j][3] + bv;
                if (J.relu) {
                    e0 = fmaxf(e0, 0.f); e1 = fmaxf(e1, 0.f);
                    e2 = fmaxf(e2, 0.f); e3 = fmaxf(e3, 0.f);
                }
                union { unsigned int u[2]; s16x4 s; } cv;
                cv.u[0] = cvtpk_bf16(e0, e1);
                cv.u[1] = cvtpk_bf16(e2, e3);
                *(s16x4*)&sb[coll * 72 + rowl] = cv.s;
            }
        }
        __syncthreads();
        int hd = t >> 2, c = (t & 3) * 16;
        int b = m0 >> 10, s0 = m0 & (S - 1), h = n0 >> 6;
        short* dst = (short*)J.out + (((size_t)(b * H + h) * HD + hd) * S + s0 + c);
        *(short8*)&dst[0] = *(const short8*)&sb[hd * 72 + c];
        *(short8*)&dst[8] = *(const short8*)&sb[hd * 72 + c + 8];
    } else {
        #pragma unroll
        for (int j = 0; j < 2; j++) {
            int col = n0 + wn + j * 16 + l16;
            float bv = loadin(J.bias, col, f);
            float rsc = 1.f, rsh = 0.f;
            if (J.rnorm) {
                float mean = J.bnsums[col] * (1.0f / (float)MROWS);
                float var = J.bnsums[D + col] * (1.0f / (float)MROWS) - mean * mean;
                rsc = rsqrtf(var + 1e-5f) * loadin(J.bng, col, f);
                rsh = loadin(J.bnb, col, f) - mean * rsc;
            }
            float s1 = 0.f, s2 = 0.f;
            #pragma unroll
            for (int i = 0; i < 2; i++) {
                int rowb = m0 + wm + i * 16 + quad * 4;
                #pragma unroll
                for (int r = 0; r < 4; r++) {
                    float v = acc[i][j][r] + bv;
                    if (J.relu) v = fmaxf(v, 0.f);
                    int row = rowb + r;
                    if (J.mode == 2) {
                        size_t idx = (size_t)row * D + col;
                        if (J.resid) {
                            float rv = J.resid[idx];
                            v += J.rnorm ? (rv * rsc + rsh) : rv;
                        }
                        ((float*)J.out)[idx] = v;
                        s1 += v;
                        s2 += v * v;
                    } else if (J.mode == 1) {
                        size_t idx = (((size_t)(row >> 10) * H + (col >> 6)) * S + (row & (S - 1))) * HD + (col & 63);
                        ((short*)J.out)[idx] = f2bs(v);
                    } else {
                        ((short*)J.out)[(size_t)row * D + col] = f2bs(v);
                    }
                }
            }
            if (J.mode == 2 && J.sacc) {
                s1 += __shfl_xor(s1, 16); s1 += __shfl_xor(s1, 32);
                s2 += __shfl_xor(s2, 16); s2 += __shfl_xor(s2, 32);
                if (quad == 0) {
                    atomicAdd(&J.sacc[col], s1);
                    atomicAdd(&J.sacc[D + col], s2);
                }
            }
        }
    }
}

// ======================= MFMA flash attention: swapped QK^T (S^T), KVBLK=128, reg-dbuf, 4 waves =======================
// mfma(K,Q) lands P row-per-lane (q=l16): in-lane max3 tree + 2 shuffles; P packed via cvt_pk.
// grid: (B*H, S/64) — bh fastest so all q-tiles of one head share an XCD (K/V L2-resident)
__global__ __launch_bounds__(256) void mfma_attn_fo_k(const short* __restrict__ Q,
                                                      const short* __restrict__ Km,
                                                      const short* __restrict__ Vt,
                                                      void* __restrict__ out,
                                                      const float* __restrict__ resid,
                                                      const float* __restrict__ rsums,
                                                      const void* __restrict__ rg,
                                                      const void* __restrict__ rb,
                                                      float* __restrict__ sacc,
                                                      float scale, int obf,
                                                      const int* __restrict__ flg) {
    __shared__ __align__(16) short Ks[128 * 64];
    __shared__ __align__(16) short Vs[64 * 128];
    __shared__ __align__(16) short Ps[4][16 * 136];
    const int fl = *flg;
    const int qt = blockIdx.y;
    const int bh = blockIdx.x;
    const int b = bh / H, h = bh % H;
    const int t = threadIdx.x;
    const int wave = t >> 6, lane = t & 63, quad = lane >> 4, l16 = lane & 15;
    const float sc2 = scale * 1.44269504089f;     // scale folded into exp2 arg
    const short* Qh = Q + (size_t)bh * S * HD;
    const short* Kh = Km + (size_t)bh * S * HD;
    const short* Vh = Vt + (size_t)bh * S * HD;
    const int qrow = qt * 64 + wave * 16 + l16;
    short8 qf0 = *(const short8*)&Qh[(size_t)qrow * 64 + quad * 8];
    short8 qf1 = *(const short8*)&Qh[(size_t)qrow * 64 + 32 + quad * 8];
    short8 ones;
    #pragma unroll
    for (int j = 0; j < 8; j++) ones[j] = (short)0x3F80;   // bf16 1.0
    f32x4 o[4];
    f32x4 ls = f32x4{0.f, 0.f, 0.f, 0.f};
    float m_i = -1e30f;                            // running max for q = wave*16 + l16
    #pragma unroll
    for (int nt = 0; nt < 4; nt++) o[nt] = f32x4{0.f, 0.f, 0.f, 0.f};
    const int krow = t >> 1, kc0 = (t & 1) * 32;   // K tile: 128 rows x 64
    const int vhd = t >> 2, vkc = (t & 3) * 32;    // V tile: 64 rows x 128
    const short* kbase = &Kh[(size_t)krow * 64 + kc0];
    const short* vbase = &Vh[(size_t)vhd * S + vkc];

    short8 kreg[4], vreg[4];
    // prologue: stage tile 0
    #pragma unroll
    for (int j = 0; j < 4; j++) kreg[j] = *(const short8*)&kbase[j * 8];
    #pragma unroll
    for (int j = 0; j < 4; j++) vreg[j] = *(const short8*)&vbase[j * 8];
    #pragma unroll
    for (int j = 0; j < 4; j++)
        *(short8*)&Ks[krow * 64 + SWZ64(krow, kc0 + j * 8)] = kreg[j];
    #pragma unroll
    for (int j = 0; j < 4; j++)
        *(short8*)&Vs[vhd * 128 + SWZ128(vhd, vkc + j * 8)] = vreg[j];
    __syncthreads();

    for (int kt = 0; kt < S; kt += 128) {
        // issue next-tile loads early (latency hides under QK^T/softmax/PV)
        if (kt + 128 < S) {
            #pragma unroll
            for (int j = 0; j < 4; j++)
                kreg[j] = *(const short8*)&kbase[(size_t)(kt + 128) * 64 + j * 8];
            #pragma unroll
            for (int j = 0; j < 4; j++)
                vreg[j] = *(const short8*)&vbase[kt + 128 + j * 8];
        }
        // swapped QK^T: D = K·Q^T = S^T.  sf[nt][r] holds (k = nt*16+quad*4+r, q = l16)
        f32x4 sf[8];
        #pragma unroll
        for (int nt = 0; nt < 8; nt++) {
            int kr = nt * 16 + l16;
            short8 kb0 = *(const short8*)&Ks[kr * 64 + SWZ64(kr, quad * 8)];
            short8 kb1 = *(const short8*)&Ks[kr * 64 + SWZ64(kr, 32 + quad * 8)];
            f32x4 c = f32x4{0.f, 0.f, 0.f, 0.f};
            c = MFMA16(kb0, qf0, c);
            c = MFMA16(kb1, qf1, c);
            sf[nt] = c;      // raw scores
        }
        // in-lane max tree via v_max3 (32 values, one q per lane) + 2 cross-quad shuffles
        float mr[4];
        #pragma unroll
        for (int r = 0; r < 4; r++) {
            float a = fmax3(sf[0][r], sf[1][r], sf[2][r]);
            float bm = fmax3(sf[3][r], sf[4][r], sf[5][r]);
            float c = fmaxf(sf[6][r], sf[7][r]);
            mr[r] = fmax3(a, bm, c);
        }
        float mx = fmaxf(fmax3(mr[0], mr[1], mr[2]), mr[3]);
        mx = fmaxf(mx, __shfl_xor(mx, 16));
        mx = fmaxf(mx, __shfl_xor(mx, 32));
        // defer-max: rescale only if this row's max grew past threshold
        bool need = ((mx - m_i) * sc2 > 8.0f);
        if (__any(need)) {
            float mnew = fmaxf(m_i, mx);
            float alpha = exp2f((m_i - mnew) * sc2);
            m_i = mnew;
            #pragma unroll
            for (int r = 0; r < 4; r++) {
                float ar = __shfl(alpha, quad * 4 + r);   // alpha for q = quad*4+r
                ls[r] *= ar;
                #pragma unroll
                for (int nt = 0; nt < 4; nt++) o[nt][r] *= ar;
            }
        }
        // P pack: exp2 + HW packed cvt, one uint2 (b64) write per nt
        #pragma unroll
        for (int nt = 0; nt < 8; nt++) {
            float e0 = exp2f((sf[nt][0] - m_i) * sc2);
            float e1 = exp2f((sf[nt][1] - m_i) * sc2);
            float e2 = exp2f((sf[nt][2] - m_i) * sc2);
            float e3 = exp2f((sf[nt][3] - m_i) * sc2);
            unsigned int w0 = cvtpk_bf16(e0, e1);
            unsigned int w1 = cvtpk_bf16(e2, e3);
            *(uint2*)&Ps[wave][l16 * 136 + nt * 16 + quad * 4] = make_uint2(w0, w1);
        }
        short8 pa[4];
        #pragma unroll
        for (int kc = 0; kc < 4; kc++)
            pa[kc] = *(const short8*)&Ps[wave][l16 * 136 + kc * 32 + quad * 8];
        #pragma unroll
        for (int nt = 0; nt < 4; nt++) {
            int vr = nt * 16 + l16;
            #pragma unroll
            for (int kc = 0; kc < 4; kc++) {
                short8 vb = *(const short8*)&Vs[vr * 128 + SWZ128(vr, kc * 32 + quad * 8)];
                o[nt] = MFMA16(pa[kc], vb, o[nt]);
            }
        }
        // softmax denominator via MFMA: ls += P . 1  (ls[r] is q = quad*4+r, matches o)
        #pragma unroll
        for (int kc = 0; kc < 4; kc++) ls = MFMA16(pa[kc], ones, ls);
        __syncthreads();   // all waves done reading Ks/Vs
        if (kt + 128 < S) {
            #pragma unroll
            for (int j = 0; j < 4; j++)
                *(short8*)&Ks[krow * 64 + SWZ64(krow, kc0 + j * 8)] = kreg[j];
            #pragma unroll
            for (int j = 0; j < 4; j++)
                *(short8*)&Vs[vhd * 128 + SWZ128(vhd, vkc + j * 8)] = vreg[j];
        }
        __syncthreads();   // next tile visible
    }
    float inv[4];
    #pragma unroll
    for (int r = 0; r < 4; r++) inv[r] = 1.0f / ls[r];
    #pragma unroll
    for (int nt = 0; nt < 4; nt++) {
        int col = h * HD + nt * 16 + l16;
        float rsc = 1.f, rsh = 0.f;
        if (rsums) {
            float mean = rsums[col] * (1.0f / (float)MROWS);
            float var = rsums[D + col] * (1.0f / (float)MROWS) - mean * mean;
            rsc = rsqrtf(var + 1e-5f) * loadin(rg, col, fl);
            rsh = loadin(rb, col, fl) - mean * rsc;
        }
        float s1 = 0.f, s2 = 0.f;
        #pragma unroll
        for (int r = 0; r < 4; r++) {
            int row = b * S + qt * 64 + wave * 16 + quad * 4 + r;
            size_t idx = (size_t)row * D + col;
            float v = o[nt][r] * inv[r];
            if (obf) {
                ((short*)out)[idx] = f2bs(v);
            } else {
                if (resid) {
                    float rv = resid[idx];
                    v += rsums ? (rv * rsc + rsh) : rv;
                }
                ((float*)out)[idx] = v;
                s1 += v;
                s2 += v * v;
            }
        }
        if (sacc) {
            s1 += __shfl_xor(s1, 16); s1 += __shfl_xor(s1, 32);
            s2 += __shfl_xor(s2, 16); s2 += __shfl_xor(s2, 32);
            if (quad == 0) {
                atomicAdd(&sacc[col], s1);
                atomicAdd(&sacc[D + col], s2);
            }
        }
    }
}

extern "C" void kernel_launch(void* const* d_in, const int* in_sizes, int n_in,
                              void* d_out, int out_size, void* d_ws, size_t ws_size,
                              hipStream_t stream) {
    const int* x = (const int*)d_in[0];
    const short* encod = (const short*)d_in[1];
    const short* embed = (const short*)d_in[2];
    const short* Wq = (const short*)d_in[3];
    const short* bq = (const short*)d_in[4];
    const short* Wk = (const short*)d_in[5];
    const short* bk = (const short*)d_in[6];
    const short* Wv = (const short*)d_in[7];
    const short* bv = (const short*)d_in[8];
    const short* g1 = (const short*)d_in[9];
    const short* b1 = (const short*)d_in[10];
    const short* Wq2 = (const short*)d_in[11];
    const short* bq2 = (const short*)d_in[12];
    const short* Wk2 = (const short*)d_in[13];
    const short* bk2 = (const short*)d_in[14];
    const short* Wv2 = (const short*)d_in[15];
    const short* bv2 = (const short*)d_in[16];
    const short* Wo2 = (const short*)d_in[17];
    const short* bo2 = (const short*)d_in[18];
    const short* g2 = (const short*)d_in[19];
    const short* b2 = (const short*)d_in[20];
    const short* Wf = (const short*)d_in[21];
    const short* bf_ = (const short*)d_in[22];

    // ---- workspace layout in half-BUF (hb = NELEM shorts) units ----
    short* HBase = (short*)d_ws;
    #define HB(i) (HBase + (size_t)(i) * NELEM)
    float* IMf = (float*)HB(0);        // hb0-1  fp32 input_multi (iter0 resid)
    short* IMb = HB(2);                // hb2    bf16 operand copy (iter0 self-proj A)
    short* Q2h = HB(3);                // hb3    persistent cross Q (bf16 head layout)
    short* K2h = HB(4);                // hb4    persistent cross K
    short* WTp = HB(5);                // hb5    packed transposed bf16 weights
    short* WTq  = WTp;                 // [768][256]
    short* WTk  = WTp + 196608;
    short* WTv  = WTp + 393216;
    short* WTq2 = WTp + 589824;        // [768][384]
    short* WTk2 = WTp + 884736;
    short* WTv2 = WTp + 1179648;       // [768][768]
    short* WTo2 = WTp + 1769472;
    short* WTf  = WTp + 2359296;
    short* Qbh = HB(6);                // hb6    self Q (bf16 head); Eb pre-loop
    short* Kbh = HB(7);                // hb7    self K
    short* Vth = HB(9);                // hb9    V transposed [B,H,64,S]
    float* T1f = (float*)HB(10);       // hb10-11 raw BN1 input (IM+sa)
    float* Ff  = (float*)HB(12);       // hb12-13 raw BN3 input (t2+ffn)
    short* A2b = HB(15);               // hb15   cross-attn out bf16
    float* T2f = (float*)HB(16);       // hb16-17 raw BN2 input (m2+t)
    short* Eb  = Qbh;                  // pre-loop: encod bf16
    float* SU = (float*)HB(18);        // 6 sums buffers
    #define SUMS(it, bn) (SU + (size_t)((it) * 3 + (bn)) * 2 * D)
    int*   flg  = (int*)(SU + 12 * D);

    const dim3 gGrid(12, 64);                // 768 blocks = 3/CU
    const dim3 aGrid(B * H, S / 64);         // bh fastest -> XCD-local K/V
    const int EB4 = (NELEM / 4 + 255) / 256;
    const float scale1 = 0.03608439182435161f;   // 1/sqrt(768)
    const float scale2 = 0.125f;                 // 1/sqrt(64)

    detect_k<<<1, 64, 0, stream>>>(encod, flg);
    embed_pos_k<<<MROWS, 256, 0, stream>>>(x, embed, IMf, IMb, flg);

    // fused: 8 weight transposes + encod convert + sums zero (one dispatch)
    WSegs sg;
    sg.src[0] = Wq;  sg.dst[0] = WTq;  sg.K[0] = 256;
    sg.src[1] = Wk;  sg.dst[1] = WTk;  sg.K[1] = 256;
    sg.src[2] = Wv;  sg.dst[2] = WTv;  sg.K[2] = 256;
    sg.src[3] = Wq2; sg.dst[3] = WTq2; sg.K[3] = 384;
    sg.src[4] = Wk2; sg.dst[4] = WTk2; sg.K[4] = 384;
    sg.src[5] = Wv2; sg.dst[5] = WTv2; sg.K[5] = 768;
    sg.src[6] = Wo2; sg.dst[6] = WTo2; sg.K[6] = 768;
    sg.src[7] = Wf;  sg.dst[7] = WTf;  sg.K[7] = 768;
    sg.esrc = encod; sg.edst = Eb; sg.statz = SU;
    prep_k<<<dim3(12, 12, 9), 256, 0, stream>>>(sg, flg);

    // cross-attn Q/K projections (persistent, bf16 head layout) — merged z=2
    {
        GJobs js;
        js.j[0] = GJob{Eb,       WTq2, bq2, Q2h, nullptr, nullptr, nullptr, nullptr, nullptr, 384, 0, 0, 1, 0, 0};
        js.j[1] = GJob{Eb + 384, WTk2, bk2, K2h, nullptr, nullptr, nullptr, nullptr, nullptr, 384, 0, 0, 1, 0, 0};
        js.j[2] = js.j[0];
        mgemm_k<<<dim3(12, 64, 2), 256, 0, stream>>>(js, flg);
    }

    for (int it = 0; it < 2; it++) {
        // self-attn projections: Q,K head layout; V directly transposed (merged z=3)
        {
            GJobs js;
            if (it == 0) {
                js.j[0] = GJob{IMb,       WTq, bq, Qbh, nullptr, nullptr, nullptr, nullptr, nullptr, 256, 0,   1, 1, 0, 0};
                js.j[1] = GJob{IMb + 256, WTk, bk, Kbh, nullptr, nullptr, nullptr, nullptr, nullptr, 256, 0,   1, 1, 0, 0};
                js.j[2] = GJob{IMb + 512, WTv, bv, Vth, nullptr, nullptr, nullptr, nullptr, nullptr, 256, 0,   1, 3, 0, 0};
            } else {
                js.j[0] = GJob{Ff, WTq, bq, Qbh, nullptr, SUMS(0, 2), g2, b2, nullptr, 256, 0,   1, 1, 1, 0};
                js.j[1] = GJob{Ff, WTk, bk, Kbh, nullptr, SUMS(0, 2), g2, b2, nullptr, 256, 256, 1, 1, 1, 0};
                js.j[2] = GJob{Ff, WTv, bv, Vth, nullptr, SUMS(0, 2), g2, b2, nullptr, 256, 512, 1, 3, 1, 0};
            }
            mgemm_k<<<dim3(12, 64, 3), 256, 0, stream>>>(js, flg);
        }
        // T1f = resid + sa  (BN1 sums accumulated)
        if (it == 0)
            mfma_attn_fo_k<<<aGrid, 256, 0, stream>>>(Qbh, Kbh, Vth, T1f, IMf,
                    nullptr, nullptr, nullptr, SUMS(0, 0), scale1, 0, flg);
        else
            mfma_attn_fo_k<<<aGrid, 256, 0, stream>>>(Qbh, Kbh, Vth, T1f, Ff,
                    SUMS(0, 2), g2, b2, SUMS(1, 0), scale1, 0, flg);
        // V2 = bn1(T1f) @ Wv2 -> transposed into Vth
        {
            GJobs js;
            js.j[0] = GJob{T1f, WTv2, bv2, Vth, nullptr, SUMS(it, 0), g1, b1, nullptr, 768, 0, 0, 3, 1, 0};
            js.j[1] = js.j[0]; js.j[2] = js.j[0];
            mgemm_k<<<gGrid, 256, 0, stream>>>(js, flg);
        }
        mfma_attn_fo_k<<<aGrid, 256, 0, stream>>>(Q2h, K2h, Vth, A2b, nullptr,
                nullptr, nullptr, nullptr, nullptr, scale2, 1, flg);
        // T2f = attn2 @ Wo2 + bn1(T1f)  (BN2 sums accumulated)
        {
            GJobs js;
            js.j[0] = GJob{A2b, WTo2, bo2, T2f, T1f, SUMS(it, 0), g1, b1, SUMS(it, 1), 768, 0, 0, 2, 0, 1};
            js.j[1] = js.j[0]; js.j[2] = js.j[0];
            mgemm_k<<<gGrid, 256, 0, stream>>>(js, flg);
        }
        // Ff = bn2(T2f) @ Wf + bn2(T2f)  (BN3 sums accumulated)
        {
            GJobs js;
            js.j[0] = GJob{T2f, WTf, bf_, Ff, T2f, SUMS(it, 1), g2, b2, SUMS(it, 2), 768, 0, 0, 2, 1, 1};
            js.j[1] = js.j[0]; js.j[2] = js.j[0];
            mgemm_k<<<gGrid, 256, 0, stream>>>(js, flg);
        }
    }

    store_norm_k<<<EB4, 256, 0, stream>>>(Ff, SUMS(1, 2), g2, b2, d_out, flg);
}